// Round 7
// baseline (71.930 us; speedup 1.0000x reference)
//
#include <hip/hip_runtime.h>

// ---------------------------------------------------------------------------
// TextureAnalysisModule: x (16,3,1024,1024) f32
//  k_score    : per-(patch, slice, half-strip) |dx|,|dy| partial sums.
//               16-row strips -> 3072 blocks -> full 32-wave/CU occupancy.
//  k_finalize : one block per patch; 2x96 partials per quantity, parallel loads
//  k_rank     : stable rank-by-counting, scatter top9/bot9 indices
//  k_output   : gather patches -> R -> H (x-bilerp) -> U (y-bilerp) -> 3x3 SRM
//               TILE=4 output rows per block -> 5376 blocks
//  out: (2,16,3,224,224) f32
// ---------------------------------------------------------------------------

#define NSLICE 48
#define IMG    1048576
#define TILE   4

// --- K1: one block per (patch-row, slice, 16-row half). --------------------
// sub=0: rows 0..15 (+halo row 16 for dy pair (15,16)), dy pairs 0..15.
// sub=1: rows 16..31, dy pairs (16,17)..(30,31).
__global__ __launch_bounds__(256) void k_score(const float* __restrict__ x,
                                               double* __restrict__ part) {
  const int ph  = blockIdx.x;   // patch row 0..31
  const int s   = blockIdx.y;   // slice 0..47
  const int sub = blockIdx.z;   // half 0..1
  const int t   = threadIdx.x;
  const float* base = x + (size_t)s * IMG + (size_t)ph * 32768
                        + (size_t)sub * 16384 + 4 * t;

  double s1x = 0.0, s2x = 0.0, s1y = 0.0, s2y = 0.0;
  const bool has_d3 = (t & 7) != 7;   // col 4t+3 is not a patch boundary

#define LD(r) (*(const float4*)(base + (size_t)(r) * 1024))
  // f32 tree-sum per row, single f64 add per quantity per row.
#define DX(v) { float nx = __shfl_down((v).x, 1);                              \
    float d0 = fabsf((v).y-(v).x), d1 = fabsf((v).z-(v).y),                    \
          d2 = fabsf((v).w-(v).z);                                             \
    float d3 = has_d3 ? fabsf(nx-(v).w) : 0.f;                                 \
    s1x += (double)((d0+d1)+(d2+d3));                                          \
    s2x += (double)((d0*d0+d1*d1)+(d2*d2+d3*d3)); }
#define DY(a,b) { float e0 = fabsf((b).x-(a).x), e1 = fabsf((b).y-(a).y),      \
                        e2 = fabsf((b).z-(a).z), e3 = fabsf((b).w-(a).w);      \
    s1y += (double)((e0+e1)+(e2+e3));                                          \
    s2y += (double)((e0*e0+e1*e1)+(e2*e2+e3*e3)); }

  float4 v0 = LD(0);
  for (int r = 0; r < 16; r += 8) {
    float4 w1 = LD(r + 1), w2 = LD(r + 2), w3 = LD(r + 3), w4 = LD(r + 4);
    float4 w5 = LD(r + 5), w6 = LD(r + 6), w7 = LD(r + 7);
    const bool have8 = (r + 8 < 16) || (sub == 0);   // row r+8 (halo row 16)
    float4 w8;
    if (have8) w8 = LD(r + 8);
    DX(v0); DX(w1); DX(w2); DX(w3); DX(w4); DX(w5); DX(w6); DX(w7);
    DY(v0, w1); DY(w1, w2); DY(w2, w3); DY(w3, w4);
    DY(w4, w5); DY(w5, w6); DY(w6, w7);
    if (have8) { DY(w7, w8); v0 = w8; }
  }
#undef LD
#undef DX
#undef DY

  // reduce within each 8-lane group (one patch per group)
#pragma unroll
  for (int off = 4; off > 0; off >>= 1) {
    s1x += __shfl_down(s1x, off, 8);
    s2x += __shfl_down(s2x, off, 8);
    s1y += __shfl_down(s1y, off, 8);
    s2y += __shfl_down(s2y, off, 8);
  }
  if ((t & 7) == 0) {
    const int p  = ph * 32 + (t >> 3);
    const int sp = (s << 1) | sub;    // 0..95
    part[(size_t)(0 * 96 + sp) * 1024 + p] = s1x;
    part[(size_t)(1 * 96 + sp) * 1024 + p] = s2x;
    part[(size_t)(2 * 96 + sp) * 1024 + p] = s1y;
    part[(size_t)(3 * 96 + sp) * 1024 + p] = s2y;
  }
}

// --- K2: one block per patch. Wave w reduces quantity q=w over 96 partials;
// lane<48 sums its adjacent pair, then 64-lane shfl tree. All loads parallel.
__global__ __launch_bounds__(256) void k_finalize(const double* __restrict__ part,
                                                  double* __restrict__ scores) {
  const int p    = blockIdx.x;
  const int t    = threadIdx.x;
  const int q    = t >> 6;          // wave index = quantity
  const int lane = t & 63;

  double v = 0.0;
  if (lane < NSLICE) {
    const double* b = part + (size_t)(q * 96 + 2 * lane) * 1024 + p;
    v = b[0] + b[1024];
  }

#pragma unroll
  for (int off = 32; off > 0; off >>= 1) v += __shfl_down(v, off);

  __shared__ double S[4];
  if (lane == 0) S[q] = v;
  __syncthreads();

  if (t == 0) {
    const double N = 47616.0;  // 16*3*32*31
    double mx = S[0] / N, my = S[2] / N;
    double vx = (S[1] - S[0] * S[0] / N) / (N - 1.0);
    double vy = (S[3] - S[2] * S[2] / N) / (N - 1.0);
    scores[p] = 0.25 * (mx + my) * (vx + vy);
  }
}

// --- K3: stable rank; 8 lanes per candidate, 32 candidates per block. ------
// sel[0..8] = rich (ranks 1015..1023 asc), sel[9..17] = poor (ranks 0..8 asc).
__global__ __launch_bounds__(256) void k_rank(const double* __restrict__ scores,
                                              int* __restrict__ sel) {
  __shared__ double sc[1024];
  const int t = threadIdx.x;
  for (int i = t; i < 1024; i += 256) sc[i] = scores[i];
  __syncthreads();

  const int c = blockIdx.x * 32 + (t >> 3);
  const double mine = sc[c];
  int rank = 0;
  for (int j = (t & 7); j < 1024; j += 8) {
    double vj = sc[j];
    rank += (vj < mine) || (vj == mine && j < c);
  }
#pragma unroll
  for (int off = 4; off > 0; off >>= 1) rank += __shfl_down(rank, off, 8);
  if ((t & 7) == 0) {
    if (rank < 9)          sel[9 + rank]    = c;
    else if (rank >= 1015) sel[rank - 1015] = c;
  }
}

// --- K4: one block per (image, 4-row output strip). ------------------------
// R (<=5x96 src rows) -> H (x-bilerp, <=5x224) -> U (y-bilerp, 6x224)
// -> 3x3 SRM conv with zero padding.
__global__ __launch_bounds__(256) void k_output(const float* __restrict__ x,
                                                const int* __restrict__ sel,
                                                float* __restrict__ out) {
  const int ty  = blockIdx.x;              // 0..55
  const int blk = blockIdx.y;              // 0..95 = set*48 + (b*3+c)
  const int set = blk / 48;
  const int bc  = blk % 48;
  const int y0  = ty * TILE;

  __shared__ int   i0t[224];
  __shared__ float frt[224];
  __shared__ float R[5][97];
  __shared__ float H[5][224];
  __shared__ float U[6][224];
  __shared__ int   selm[9];
  const int t = threadIdx.x;

  if (t < 9) selm[t] = sel[set * 9 + t];
  if (t < 224) {
    // src coord = (t+0.5)*96/224 - 0.5 = (3t-2)/7 ; edge renorm == clamp
    int num = 3 * t - 2;
    int i0, fr7;
    if (num < 0) { i0 = 0; fr7 = 0; }
    else {
      i0 = num / 7; fr7 = num - i0 * 7;
      if (i0 >= 95) { i0 = 95; fr7 = 0; }
    }
    i0t[t] = i0;
    frt[t] = (float)fr7 * (1.0f / 7.0f);
  }
  __syncthreads();

  const int Ylo   = max(y0 - 1, 0);
  const int Yhi   = min(y0 + TILE, 223);
  const int sy_lo = i0t[Ylo];
  const int sy_hi = min(i0t[Yhi] + 1, 95);
  const int nrows = sy_hi - sy_lo + 1;     // <= 5

  const float* src = x + (size_t)bc * IMG;
  for (int idx = t; idx < nrows * 96; idx += 256) {
    int ry = idx / 96, xx = idx - ry * 96;
    int sy = sy_lo + ry;
    int gr = sy >> 5, i = sy & 31;
    int gc = xx >> 5, j = xx & 31;
    int pidx = selm[gr * 3 + gc];
    R[ry][xx] = src[(size_t)((pidx >> 5) * 32 + i) * 1024 + (pidx & 31) * 32 + j];
  }
  __syncthreads();

  for (int idx = t; idx < nrows * 224; idx += 256) {
    int r = idx / 224, X = idx - r * 224;
    int ix0 = i0t[X], ix1 = min(ix0 + 1, 95);
    float fx = frt[X];
    float a = R[r][ix0], b = R[r][ix1];
    H[r][X] = a + fx * (b - a);
  }
  __syncthreads();

  // vertical bilerp rows Y = y0-1 .. y0+TILE  (TILE+2 = 6 rows)
  for (int idx = t; idx < (TILE + 2) * 224; idx += 256) {
    int yy = idx / 224, X = idx - yy * 224;
    int Y = y0 - 1 + yy;
    if ((unsigned)Y < 224u) {
      int a = i0t[Y] - sy_lo;
      int b = min(i0t[Y] + 1, 95) - sy_lo;
      float fy = frt[Y];
      float h0 = H[a][X], h1 = H[b][X];
      U[yy][X] = h0 + fy * (h1 - h0);
    }
  }
  __syncthreads();

  const float F[3][3] = {{-1.f, 3.f, -1.f}, {3.f, -8.f, 3.f}, {-1.f, 3.f, -1.f}};
  float* o = out + (size_t)blk * (224 * 224);
  for (int idx = t; idx < TILE * 224; idx += 256) {
    int yy = idx / 224;
    int xx = idx - yy * 224;
    int y  = y0 + yy;
    float acc = 0.f;
#pragma unroll
    for (int dy = 0; dy < 3; ++dy) {
      int Y = y + dy - 1;
      if ((unsigned)Y >= 224u) continue;
      const float* Ur = U[yy + dy];
#pragma unroll
      for (int dx = 0; dx < 3; ++dx) {
        int X = xx + dx - 1;
        if ((unsigned)X >= 224u) continue;
        acc += F[dy][dx] * Ur[X];
      }
    }
    o[(size_t)y * 224 + xx] = acc;
  }
}

extern "C" void kernel_launch(void* const* d_in, const int* in_sizes, int n_in,
                              void* d_out, int out_size, void* d_ws, size_t ws_size,
                              hipStream_t stream) {
  const float* x = (const float*)d_in[0];
  float* out = (float*)d_out;

  double* part   = (double*)d_ws;                          // 4*96*1024*8 = 3.0 MB
  double* scores = (double*)((char*)d_ws + 3145728);       // 8 KB
  int*    sel    = (int*)((char*)d_ws + 3153920);          // 72 B

  k_score   <<<dim3(32, 48, 2), 256, 0, stream>>>(x, part);
  k_finalize<<<1024, 256, 0, stream>>>(part, scores);
  k_rank    <<<32, 256, 0, stream>>>(scores, sel);
  k_output  <<<dim3(56, 96), 256, 0, stream>>>(x, sel, out);
}